// Round 1
// baseline (22.398 us; speedup 1.0000x reference)
//
#include <hip/hip_runtime.h>
#include <hip/hip_bf16.h>
#include <math.h>

// Problem constants (fixed by setup_inputs):
//   recon: [B=4, N=64, D=3] f32, gt: [B=4, M=2048, D=3] f32
//   P = N*(N-1)/2 = 2016 lower-tri pairs (i>j), 5 interp points per pair.
//   out: [B, P] f32 = 8064 elements.
#define BATCH 4
#define NPTS 64
#define MGT 2048
#define NPAIR 2016
#define NINTERP 5
#define WAVES_PER_BLOCK 4
#define THREADS (WAVES_PER_BLOCK * 64)

__global__ __launch_bounds__(THREADS)
void edge_cdis_kernel(const float* __restrict__ recon,
                      const float* __restrict__ gt,
                      float* __restrict__ out) {
    // One wave per (b, pair). All 4 waves in a block share the same batch b
    // because NPAIR % WAVES_PER_BLOCK == 0, so stage gt[b] into LDS once.
    __shared__ float gts[MGT * 3];  // 24 KB

    const int tid  = threadIdx.x;
    const int wib  = tid >> 6;       // wave index in block
    const int lane = tid & 63;
    const int gwave = blockIdx.x * WAVES_PER_BLOCK + wib;  // 0 .. B*NPAIR-1
    const int b = gwave / NPAIR;
    const int p = gwave % NPAIR;

    // Stage gt[b] -> LDS (coalesced: 256 threads x 24 floats)
    const float* __restrict__ gtb = gt + b * (MGT * 3);
    #pragma unroll
    for (int k = tid; k < MGT * 3; k += THREADS) gts[k] = gtb[k];
    __syncthreads();

    // Map flat pair index p -> (i, j) with i > j, tril row-major order:
    // p = i*(i-1)/2 + j
    int i = (int)((1.0f + sqrtf(1.0f + 8.0f * (float)p)) * 0.5f);
    while (i * (i - 1) / 2 > p) --i;
    while ((i + 1) * i / 2 <= p) ++i;
    const int j = p - i * (i - 1) / 2;

    const float* __restrict__ rb = recon + b * (NPTS * 3);
    const float sx = rb[i * 3 + 0], sy = rb[i * 3 + 1], sz = rb[i * 3 + 2];
    const float ex = rb[j * 3 + 0], ey = rb[j * 3 + 1], ez = rb[j * 3 + 2];

    // K_t = start * f + end * (1 - f), f = t/4  (same formula order as ref)
    float Kx[NINTERP], Ky[NINTERP], Kz[NINTERP];
    #pragma unroll
    for (int t = 0; t < NINTERP; ++t) {
        const float f = 0.25f * (float)t;
        const float g = 1.0f - f;
        Kx[t] = sx * f + ex * g;
        Ky[t] = sy * f + ey * g;
        Kz[t] = sz * f + ez * g;
    }

    float m[NINTERP];
    #pragma unroll
    for (int t = 0; t < NINTERP; ++t) m[t] = 3.4e38f;

    // Each lane covers MGT/64 = 32 gt points.
    for (int g = lane; g < MGT; g += 64) {
        const float gx = gts[g * 3 + 0];
        const float gy = gts[g * 3 + 1];
        const float gz = gts[g * 3 + 2];
        #pragma unroll
        for (int t = 0; t < NINTERP; ++t) {
            const float dx = Kx[t] - gx;
            const float dy = Ky[t] - gy;
            const float dz = Kz[t] - gz;
            const float d = fmaf(dz, dz, fmaf(dy, dy, dx * dx));
            m[t] = fminf(m[t], d);
        }
    }

    // Wave-wide min reduction (64 lanes)
    #pragma unroll
    for (int t = 0; t < NINTERP; ++t) {
        #pragma unroll
        for (int off = 32; off >= 1; off >>= 1) {
            m[t] = fminf(m[t], __shfl_xor(m[t], off, 64));
        }
    }

    if (lane == 0) {
        out[gwave] = (m[0] + m[1] + m[2] + m[3] + m[4]) * 0.2f;
    }
}

extern "C" void kernel_launch(void* const* d_in, const int* in_sizes, int n_in,
                              void* d_out, int out_size, void* d_ws, size_t ws_size,
                              hipStream_t stream) {
    const float* recon = (const float*)d_in[0];
    const float* gt    = (const float*)d_in[1];
    float* out = (float*)d_out;

    const int total_waves = BATCH * NPAIR;          // 8064
    const int blocks = total_waves / WAVES_PER_BLOCK; // 2016
    edge_cdis_kernel<<<blocks, THREADS, 0, stream>>>(recon, gt, out);
}

// Round 2
// 16.981 us; speedup vs baseline: 1.3190x; 1.3190x over previous
//
#include <hip/hip_runtime.h>
#include <hip/hip_bf16.h>
#include <math.h>

// recon: [B=4, N=64, D=3] f32, gt: [B=4, M=2048, D=3] f32
// P = 2016 tril pairs (i>j); 5 interp points; out [B,P] f32.
//
// Key algebra: K(f) = s*f + e*(1-f);  K(f)-g = (e-g) + f*(s-e)
//   d(f) = a + f*w2 + f^2*c   with a=||e-g||^2, w2=2(e-g)o(s-e), c=||s-e||^2
//   f in {0, .25, .5, .75, 1}:  d(0)=a, d(1)=a+w2+c, middle via fma.
// Per-pair constants (s-e, c, u_t=f_t^2*c) are wave-uniform -> SGPRs.
#define BATCH 4
#define NPTS 64
#define MGT 2048
#define NPAIR 2016
#define PPW 2                      // pairs per wave
#define WAVES_PER_BLOCK 4
#define THREADS (WAVES_PER_BLOCK * 64)
#define PAIRS_PER_BLOCK (WAVES_PER_BLOCK * PPW)   // 8

__global__ __launch_bounds__(THREADS)
void edge_cdis_kernel(const float* __restrict__ recon,
                      const float* __restrict__ gt,
                      float* __restrict__ out) {
    // gt[b] staged as float4-padded AoS: 2048 x 16B = 32 KB
    __shared__ float4 gts4[MGT];

    const int tid  = threadIdx.x;
    const int wib  = tid >> 6;
    const int lane = tid & 63;

    // 8 consecutive global pair-slots per block; 2016 % 8 == 0 so the whole
    // block is in one batch.
    const int q0 = blockIdx.x * PAIRS_PER_BLOCK;   // global pair slot
    const int b  = q0 / NPAIR;

    // Stage gt[b] -> padded LDS. Thread k handles points k, k+256, ...
    const float* __restrict__ gtb = gt + b * (MGT * 3);
    #pragma unroll
    for (int p = tid; p < MGT; p += THREADS) {
        float4 v;
        v.x = gtb[p * 3 + 0];
        v.y = gtb[p * 3 + 1];
        v.z = gtb[p * 3 + 2];
        v.w = 0.0f;
        gts4[p] = v;
    }
    __syncthreads();

    const float* __restrict__ rb = recon + b * (NPTS * 3);

    // Per-pair (wave-uniform) setup
    float ex[PPW], ey[PPW], ez[PPW];        // end point e = recon[j]
    float sex[PPW], sey[PPW], sez[PPW];     // s - e
    float u1[PPW], u2[PPW], u3[PPW], c_[PPW];
    int qg[PPW];
    #pragma unroll
    for (int k = 0; k < PPW; ++k) {
        const int q = q0 + wib * PPW + k;
        qg[k] = q;
        const int p = q % NPAIR;
        int i = (int)((1.0f + sqrtf(1.0f + 8.0f * (float)p)) * 0.5f);
        while (i * (i - 1) / 2 > p) --i;
        while ((i + 1) * i / 2 <= p) ++i;
        const int j = p - i * (i - 1) / 2;
        const float sx = rb[i * 3 + 0], sy = rb[i * 3 + 1], sz = rb[i * 3 + 2];
        ex[k] = rb[j * 3 + 0]; ey[k] = rb[j * 3 + 1]; ez[k] = rb[j * 3 + 2];
        sex[k] = sx - ex[k]; sey[k] = sy - ey[k]; sez[k] = sz - ez[k];
        const float c = sex[k]*sex[k] + sey[k]*sey[k] + sez[k]*sez[k];
        c_[k] = c;
        u1[k] = 0.0625f * c;   // (0.25)^2 c
        u2[k] = 0.25f   * c;   // (0.5)^2 c
        u3[k] = 0.5625f * c;   // (0.75)^2 c
    }

    float m[PPW][5];
    #pragma unroll
    for (int k = 0; k < PPW; ++k)
        #pragma unroll
        for (int t = 0; t < 5; ++t) m[k][t] = 3.4e38f;

    // Each lane covers 32 gt points.
    #pragma unroll 4
    for (int g = lane; g < MGT; g += 64) {
        const float4 gv = gts4[g];
        #pragma unroll
        for (int k = 0; k < PPW; ++k) {
            const float dx = ex[k] - gv.x;
            const float dy = ey[k] - gv.y;
            const float dz = ez[k] - gv.z;
            float a = dx * dx;
            a = fmaf(dy, dy, a);
            a = fmaf(dz, dz, a);
            float b2 = dx * sex[k];
            b2 = fmaf(dy, sey[k], b2);
            b2 = fmaf(dz, sez[k], b2);
            const float w2 = b2 + b2;
            m[k][0] = fminf(m[k][0], a);                       // f=0
            m[k][1] = fminf(m[k][1], fmaf(0.25f, w2, a + u1[k]));
            m[k][2] = fminf(m[k][2], fmaf(0.50f, w2, a + u2[k]));
            m[k][3] = fminf(m[k][3], fmaf(0.75f, w2, a + u3[k]));
            m[k][4] = fminf(m[k][4], (a + c_[k]) + w2);        // f=1
        }
    }

    // Wave-wide min reduction
    #pragma unroll
    for (int k = 0; k < PPW; ++k)
        #pragma unroll
        for (int t = 0; t < 5; ++t)
            #pragma unroll
            for (int off = 32; off >= 1; off >>= 1)
                m[k][t] = fminf(m[k][t], __shfl_xor(m[k][t], off, 64));

    if (lane == 0) {
        #pragma unroll
        for (int k = 0; k < PPW; ++k)
            out[qg[k]] = (m[k][0] + m[k][1] + m[k][2] + m[k][3] + m[k][4]) * 0.2f;
    }
}

extern "C" void kernel_launch(void* const* d_in, const int* in_sizes, int n_in,
                              void* d_out, int out_size, void* d_ws, size_t ws_size,
                              hipStream_t stream) {
    const float* recon = (const float*)d_in[0];
    const float* gt    = (const float*)d_in[1];
    float* out = (float*)d_out;

    const int blocks = (BATCH * NPAIR) / PAIRS_PER_BLOCK;  // 1008
    edge_cdis_kernel<<<blocks, THREADS, 0, stream>>>(recon, gt, out);
}

// Round 3
// 15.515 us; speedup vs baseline: 1.4436x; 1.0945x over previous
//
#include <hip/hip_runtime.h>
#include <hip/hip_bf16.h>
#include <math.h>

// recon: [B=4, N=64, D=3] f32, gt: [B=4, M=2048, D=3] f32
// P = 2016 tril pairs (i>j); 5 interp pts; out [B,P] f32.
//
// d(f) = ||(e-g) + f*(s-e)||^2 = a + 2f*B + f^2*c
//   a = ||e-g||^2, B = (e-g).(s-e), c = ||s-e||^2
//   f in {0,.25,.5,.75,1}: d_t = fmaf(2*f_t, B, a) + f_t^2*c
// 22 VALU ops per (pair, gt-point), per-pair constants wave-uniform.
//
// Block layout: 63 blocks per batch x 32 pair-slots each (63*32 = 2016 exact).
// 1024 threads = 16 waves, PPW=2 pairs per wave. gt[b] staged once per block
// (float4-padded, 32 KB) -> 4x less staging traffic than 256-thread blocks.
#define BATCH 4
#define NPTS 64
#define MGT 2048
#define NPAIR 2016
#define PPW 2
#define THREADS 1024
#define WAVES_PER_BLOCK 16
#define PAIRS_PER_BLOCK (WAVES_PER_BLOCK * PPW)   // 32
#define BLOCKS_PER_BATCH (NPAIR / PAIRS_PER_BLOCK) // 63

__global__ __launch_bounds__(THREADS)
void edge_cdis_kernel(const float* __restrict__ recon,
                      const float* __restrict__ gt,
                      float* __restrict__ out) {
    __shared__ float4 gts4[MGT];   // 32 KB

    const int tid  = threadIdx.x;
    const int wib  = tid >> 6;
    const int lane = tid & 63;

    const int b     = blockIdx.x / BLOCKS_PER_BATCH;
    const int pbase = (blockIdx.x % BLOCKS_PER_BATCH) * PAIRS_PER_BLOCK;

    // Stage gt[b] -> padded LDS (2 iterations with 1024 threads)
    const float* __restrict__ gtb = gt + b * (MGT * 3);
    #pragma unroll
    for (int p = tid; p < MGT; p += THREADS) {
        float4 v;
        v.x = gtb[p * 3 + 0];
        v.y = gtb[p * 3 + 1];
        v.z = gtb[p * 3 + 2];
        v.w = 0.0f;
        gts4[p] = v;
    }
    __syncthreads();

    const float* __restrict__ rb = recon + b * (NPTS * 3);

    // Per-pair wave-uniform setup
    float ex[PPW], ey[PPW], ez[PPW];      // e = recon[j]
    float ux[PPW], uy[PPW], uz[PPW];      // u = s - e
    float u1[PPW], u2[PPW], u3[PPW], c_[PPW];
    int og[PPW];
    #pragma unroll
    for (int k = 0; k < PPW; ++k) {
        const int p = pbase + wib * PPW + k;
        og[k] = b * NPAIR + p;
        int i = (int)((1.0f + sqrtf(1.0f + 8.0f * (float)p)) * 0.5f);
        while (i * (i - 1) / 2 > p) --i;
        while ((i + 1) * i / 2 <= p) ++i;
        const int j = p - i * (i - 1) / 2;
        const float sx = rb[i * 3 + 0], sy = rb[i * 3 + 1], sz = rb[i * 3 + 2];
        ex[k] = rb[j * 3 + 0]; ey[k] = rb[j * 3 + 1]; ez[k] = rb[j * 3 + 2];
        ux[k] = sx - ex[k]; uy[k] = sy - ey[k]; uz[k] = sz - ez[k];
        const float c = ux[k]*ux[k] + uy[k]*uy[k] + uz[k]*uz[k];
        c_[k] = c;
        u1[k] = 0.0625f * c;
        u2[k] = 0.25f   * c;
        u3[k] = 0.5625f * c;
    }

    float m[PPW][5];
    #pragma unroll
    for (int k = 0; k < PPW; ++k)
        #pragma unroll
        for (int t = 0; t < 5; ++t) m[k][t] = 3.4e38f;

    #pragma unroll 4
    for (int g = lane; g < MGT; g += 64) {
        const float4 gv = gts4[g];
        #pragma unroll
        for (int k = 0; k < PPW; ++k) {
            const float dx = ex[k] - gv.x;
            const float dy = ey[k] - gv.y;
            const float dz = ez[k] - gv.z;
            float a = dx * dx;
            a = fmaf(dy, dy, a);
            a = fmaf(dz, dz, a);
            float B = dx * ux[k];
            B = fmaf(dy, uy[k], B);
            B = fmaf(dz, uz[k], B);
            m[k][0] = fminf(m[k][0], a);                        // f=0
            m[k][1] = fminf(m[k][1], fmaf(0.5f, B, a) + u1[k]); // f=.25
            m[k][2] = fminf(m[k][2], (a + B) + u2[k]);          // f=.5
            m[k][3] = fminf(m[k][3], fmaf(1.5f, B, a) + u3[k]); // f=.75
            m[k][4] = fminf(m[k][4], fmaf(2.0f, B, a) + c_[k]); // f=1
        }
    }

    // Wave-wide min reduction
    #pragma unroll
    for (int k = 0; k < PPW; ++k)
        #pragma unroll
        for (int t = 0; t < 5; ++t)
            #pragma unroll
            for (int off = 32; off >= 1; off >>= 1)
                m[k][t] = fminf(m[k][t], __shfl_xor(m[k][t], off, 64));

    if (lane == 0) {
        #pragma unroll
        for (int k = 0; k < PPW; ++k)
            out[og[k]] = (m[k][0] + m[k][1] + m[k][2] + m[k][3] + m[k][4]) * 0.2f;
    }
}

extern "C" void kernel_launch(void* const* d_in, const int* in_sizes, int n_in,
                              void* d_out, int out_size, void* d_ws, size_t ws_size,
                              hipStream_t stream) {
    const float* recon = (const float*)d_in[0];
    const float* gt    = (const float*)d_in[1];
    float* out = (float*)d_out;

    const int blocks = BATCH * BLOCKS_PER_BATCH;  // 252
    edge_cdis_kernel<<<blocks, THREADS, 0, stream>>>(recon, gt, out);
}

// Round 4
// 13.156 us; speedup vs baseline: 1.7024x; 1.1793x over previous
//
#include <hip/hip_runtime.h>
#include <hip/hip_bf16.h>
#include <math.h>

// recon: [B=4, N=64, D=3] f32, gt: [B=4, M=2048, D=3] f32
// P = 2016 tril pairs (i>j); 5 interp pts f in {0,.25,.5,.75,1}; out [B,P].
//
// Algebra: K(f)-g = (e-g) + f*u,  u = s-e.
//   d(f) = ||e-g||^2 + 2f (e-g).u + f^2 ||u||^2
// Expand ||e-g||^2 = ||e||^2 - 2 e.g + ||g||^2 and divide by 2:
//   d(f)/2 = [e.gn + hh] + f*(u.gn) + (0.5||e||^2 + f*(e.u) + 0.5 f^2 c)
//            \____ T0 ___/   \_ G _/   \________ per-pair consts ________/
// with gn = -g, hh = 0.5||g||^2 stored in LDS. min over g commutes with
// adding per-pair consts, so inner loop tracks r_t = min_g(T0 + f_t*G):
//   15 VALU ops per (pair,g): 3 fma (T0) + 3 (G) + 9 (5 min-evals).
// Epilogue (exact const folding):
//   out = mean_t[2*(r_t + 0.5||e||^2 + f_t*(e.u)) + f_t^2 c]
//       = 0.4*sum(r_t) + ||e||^2 + e.u + 0.375*c
#define BATCH 4
#define NPTS 64
#define MGT 2048
#define NPAIR 2016
#define PPW 2
#define THREADS 1024
#define WAVES_PER_BLOCK 16
#define PAIRS_PER_BLOCK (WAVES_PER_BLOCK * PPW)    // 32
#define BLOCKS_PER_BATCH (NPAIR / PAIRS_PER_BLOCK) // 63

__global__ __launch_bounds__(THREADS)
void edge_cdis_kernel(const float* __restrict__ recon,
                      const float* __restrict__ gt,
                      float* __restrict__ out) {
    __shared__ float4 gts4[MGT];   // {-gx, -gy, -gz, 0.5*||g||^2}, 32 KB

    const int tid  = threadIdx.x;
    const int wib  = tid >> 6;
    const int lane = tid & 63;

    const int b     = blockIdx.x / BLOCKS_PER_BATCH;
    const int pbase = (blockIdx.x % BLOCKS_PER_BATCH) * PAIRS_PER_BLOCK;

    // Stage gt[b] -> LDS as (gn, hh)
    const float* __restrict__ gtb = gt + b * (MGT * 3);
    #pragma unroll
    for (int p = tid; p < MGT; p += THREADS) {
        const float gx = gtb[p * 3 + 0];
        const float gy = gtb[p * 3 + 1];
        const float gz = gtb[p * 3 + 2];
        float4 v;
        v.x = -gx; v.y = -gy; v.z = -gz;
        v.w = 0.5f * fmaf(gz, gz, fmaf(gy, gy, gx * gx));
        gts4[p] = v;
    }
    __syncthreads();

    const float* __restrict__ rb = recon + b * (NPTS * 3);

    // Per-pair wave-uniform setup
    float ex[PPW], ey[PPW], ez[PPW];      // e = recon[j]
    float ux[PPW], uy[PPW], uz[PPW];      // u = s - e
    float e2[PPW], eu[PPW], c_[PPW];
    int og[PPW];
    #pragma unroll
    for (int k = 0; k < PPW; ++k) {
        const int p = pbase + wib * PPW + k;
        og[k] = b * NPAIR + p;
        int i = (int)((1.0f + sqrtf(1.0f + 8.0f * (float)p)) * 0.5f);
        while (i * (i - 1) / 2 > p) --i;
        while ((i + 1) * i / 2 <= p) ++i;
        const int j = p - i * (i - 1) / 2;
        const float sx = rb[i * 3 + 0], sy = rb[i * 3 + 1], sz = rb[i * 3 + 2];
        ex[k] = rb[j * 3 + 0]; ey[k] = rb[j * 3 + 1]; ez[k] = rb[j * 3 + 2];
        ux[k] = sx - ex[k]; uy[k] = sy - ey[k]; uz[k] = sz - ez[k];
        e2[k] = ex[k]*ex[k] + ey[k]*ey[k] + ez[k]*ez[k];
        eu[k] = ex[k]*ux[k] + ey[k]*uy[k] + ez[k]*uz[k];
        c_[k] = ux[k]*ux[k] + uy[k]*uy[k] + uz[k]*uz[k];
    }

    float r[PPW][5];
    #pragma unroll
    for (int k = 0; k < PPW; ++k)
        #pragma unroll
        for (int t = 0; t < 5; ++t) r[k][t] = 3.4e38f;

    #pragma unroll 8
    for (int g = lane; g < MGT; g += 64) {
        const float4 gv = gts4[g];   // (gnx, gny, gnz, hh)
        #pragma unroll
        for (int k = 0; k < PPW; ++k) {
            // T0 = e.gn + hh   (3 fma)
            float T0 = fmaf(ex[k], gv.x, gv.w);
            T0 = fmaf(ey[k], gv.y, T0);
            T0 = fmaf(ez[k], gv.z, T0);
            // G = u.gn         (mul + 2 fma)
            float G = ux[k] * gv.x;
            G = fmaf(uy[k], gv.y, G);
            G = fmaf(uz[k], gv.z, G);
            // r_t = min(T0 + f_t * G), f_t in {0,.25,.5,.75,1}
            r[k][0] = fminf(r[k][0], T0);
            r[k][1] = fminf(r[k][1], fmaf(0.25f, G, T0));
            r[k][2] = fminf(r[k][2], fmaf(0.50f, G, T0));
            r[k][3] = fminf(r[k][3], fmaf(0.75f, G, T0));
            r[k][4] = fminf(r[k][4], T0 + G);
        }
    }

    // Wave-wide min reduction
    #pragma unroll
    for (int k = 0; k < PPW; ++k)
        #pragma unroll
        for (int t = 0; t < 5; ++t)
            #pragma unroll
            for (int off = 32; off >= 1; off >>= 1)
                r[k][t] = fminf(r[k][t], __shfl_xor(r[k][t], off, 64));

    if (lane == 0) {
        #pragma unroll
        for (int k = 0; k < PPW; ++k) {
            const float sr = r[k][0] + r[k][1] + r[k][2] + r[k][3] + r[k][4];
            out[og[k]] = 0.4f * sr + e2[k] + eu[k] + 0.375f * c_[k];
        }
    }
}

extern "C" void kernel_launch(void* const* d_in, const int* in_sizes, int n_in,
                              void* d_out, int out_size, void* d_ws, size_t ws_size,
                              hipStream_t stream) {
    const float* recon = (const float*)d_in[0];
    const float* gt    = (const float*)d_in[1];
    float* out = (float*)d_out;

    const int blocks = BATCH * BLOCKS_PER_BATCH;  // 252
    edge_cdis_kernel<<<blocks, THREADS, 0, stream>>>(recon, gt, out);
}